// Round 4
// baseline (483.456 us; speedup 1.0000x reference)
//
#include <hip/hip_runtime.h>
#include <hip/hip_bf16.h>

using bf16x8 = __attribute__((ext_vector_type(8))) short;
using f32x4  = __attribute__((ext_vector_type(4))) float;

#define MFMA16(a, b, c) __builtin_amdgcn_mfma_f32_16x16x32_bf16((a), (b), (c), 0, 0, 0)

__device__ __forceinline__ short f2b(float f) {   // RNE bf16
    unsigned u = __builtin_bit_cast(unsigned, f);
    u = (u + 0x7fffu + ((u >> 16) & 1u)) >> 16;
    return (short)u;
}
__device__ __forceinline__ short pkb(float f) {   // round-to-nearest, ties away
    return (short)((__builtin_bit_cast(unsigned, f) + 0x8000u) >> 16);
}
__device__ __forceinline__ unsigned pk2(float lo, float hi) {  // two bf16 -> dword
    return (unsigned)(unsigned short)pkb(lo) | ((unsigned)(unsigned short)pkb(hi) << 16);
}
__device__ __forceinline__ void gl_lds16(const short* g, short* l) {
    __builtin_amdgcn_global_load_lds(
        (const __attribute__((address_space(1))) unsigned int*)g,
        (__attribute__((address_space(3))) unsigned int*)l, 16, 0, 0);
}

// ---------------- cast kernels ----------------
__global__ __launch_bounds__(256)
void cast_x_kernel(const float* __restrict__ x, short* __restrict__ xb) {
    const int i = blockIdx.x * 256 + threadIdx.x;   // float4 index, grid exact
    const float4 v = ((const float4*)x)[i];
    short4 o;
    o.x = f2b(v.x); o.y = f2b(v.y); o.z = f2b(v.z); o.w = f2b(v.w);
    ((short4*)xb)[i] = o;
}

__global__ __launch_bounds__(256)
void cast_w_kernel(const float* __restrict__ wqkv, const float* __restrict__ wproj,
                   short* __restrict__ wqT, short* __restrict__ wpT) {
    const int t = blockIdx.x * 256 + threadIdx.x;
    if (t < 768 * 256) {
        const int n = t >> 8, k = t & 255;
        float v = wqkv[k * 768 + n];
        if (n < 256) v *= 0.17677669529663687f;    // fold 1/sqrt(hd) into q columns
        wqT[t] = f2b(v);
    } else {
        const int u = t - 768 * 256;               // u < 65536
        const int n = u >> 8, k = u & 255;
        wpT[u] = f2b(wproj[k * 256 + n]);
    }
}

// ---------------- QKV GEMM: [131072 x 256] x [768 x 256]^T, scatter-epilogue ----------------
// XCD swizzle: all 6 n-blocks of one m-block run adjacent on the same XCD (id%8).
__global__ __launch_bounds__(256)
void gemm_qkv_kernel(const short* __restrict__ A, const short* __restrict__ Bt,
                     short* __restrict__ qkvL, short* __restrict__ qkvG) {
    __shared__ short As[128 * 32];
    __shared__ short Bs[128 * 32];
    const int tid  = threadIdx.x;
    const int lane = tid & 63, wave = tid >> 6;
    const int wm = wave >> 1, wn = wave & 1;
    const int quad = lane >> 4, l16 = lane & 15;
    const int id = blockIdx.x;
    const int qq = id >> 3, xcd = id & 7;
    const int m0 = (xcd * 128 + qq / 6) * 128;
    const int n0 = (qq % 6) * 128;

    const f32x4 zf = {0.f, 0.f, 0.f, 0.f};
    f32x4 acc[4][4];
#pragma unroll
    for (int i = 0; i < 4; ++i)
#pragma unroll
        for (int j = 0; j < 4; ++j) acc[i][j] = zf;

    const int srow = wave * 16 + (lane >> 2);
    const int scol = (lane & 3) * 8;
    const short* Ap = A  + (long)(m0 + srow) * 256 + scol;
    const short* Bp = Bt + (long)(n0 + srow) * 256 + scol;
    short* lA = &As[wave * 512];
    short* lB = &Bs[wave * 512];

    for (int kt = 0; kt < 8; ++kt) {
        const int off = kt * 32;
        __syncthreads();
        gl_lds16(Ap + off,            lA);
        gl_lds16(Ap + 64 * 256 + off, lA + 2048);
        gl_lds16(Bp + off,            lB);
        gl_lds16(Bp + 64 * 256 + off, lB + 2048);
        __syncthreads();
        bf16x8 af[4], bfr[4];
#pragma unroll
        for (int i = 0; i < 4; ++i)
            af[i] = *(const bf16x8*)&As[(wm * 64 + i * 16 + l16) * 32 + quad * 8];
#pragma unroll
        for (int j = 0; j < 4; ++j)
            bfr[j] = *(const bf16x8*)&Bs[(wn * 64 + j * 16 + l16) * 32 + quad * 8];
#pragma unroll
        for (int i = 0; i < 4; ++i)
#pragma unroll
            for (int j = 0; j < 4; ++j)
                acc[i][j] = MFMA16(af[i], bfr[j], acc[i][j]);
    }

    // scatter epilogue; dword stores via lane-pairing (even l16 stores ch,ch+1)
    const int part = n0 >> 8;                      // 0=q 1=k 2=v
    const bool isLocal = ((n0 >> 7) & 1) == 0;     // cols%256 < 128 -> heads 0..3
    const bool evenL = (l16 & 1) == 0;
    if (isLocal) {
        short* base = qkvL + part * 2048;          // [sh][part][64][32]
#pragma unroll
        for (int i = 0; i < 4; ++i)
#pragma unroll
            for (int r = 0; r < 4; ++r) {
                const int token = m0 + wm * 64 + i * 16 + quad * 4 + r;
                const int b = token >> 14, hw = token & 16383;
                const int hrow = hw >> 7, wcol = hw & 127;
                const int win = ((hrow >> 3) << 4) + (wcol >> 3);
                const int ti  = ((hrow & 7) << 3) + (wcol & 7);
                const long shb = (long)((b << 8) + win) << 2;
#pragma unroll
                for (int j = 0; j < 4; ++j) {
                    const float v = acc[i][j][r];
                    const float w = __shfl_xor(v, 1);
                    if (evenL) {
                        const int c128 = wn * 64 + j * 16 + l16;   // even
                        const int head = c128 >> 5, ch = c128 & 31;
                        *(unsigned*)&base[(shb + head) * 6144 + ti * 32 + ch] = pk2(v, w);
                    }
                }
            }
    } else {
        short* base = qkvG + part * 8192;          // [sh][part][256][32]
#pragma unroll
        for (int i = 0; i < 4; ++i)
#pragma unroll
            for (int r = 0; r < 4; ++r) {
                const int token = m0 + wm * 64 + i * 16 + quad * 4 + r;
                const int b = token >> 14, hw = token & 16383;
                const int hrow = hw >> 7, wcol = hw & 127;
                const int pos = ((hrow & 7) << 3) + (wcol & 7);
                const int ti  = ((hrow >> 3) << 4) + (wcol >> 3);
                const long shb = (long)((b << 6) + pos) << 2;
#pragma unroll
                for (int j = 0; j < 4; ++j) {
                    const float v = acc[i][j][r];
                    const float w = __shfl_xor(v, 1);
                    if (evenL) {
                        const int c128 = wn * 64 + j * 16 + l16;   // even
                        const int head = c128 >> 5, ch = c128 & 31;
                        *(unsigned*)&base[(shb + head) * 24576 + ti * 32 + ch] = pk2(v, w);
                    }
                }
            }
    }
}

// ---------------- proj GEMM: [131072 x 256] x [256 x 256]^T + bias, fp32 out ----------------
__global__ __launch_bounds__(256)
void gemm_proj_kernel(const short* __restrict__ A, const short* __restrict__ Bt,
                      float* __restrict__ C, const float* __restrict__ bias) {
    __shared__ short As[128 * 32];
    __shared__ short Bs[128 * 32];
    const int tid  = threadIdx.x;
    const int lane = tid & 63, wave = tid >> 6;
    const int wm = wave >> 1, wn = wave & 1;
    const int quad = lane >> 4, l16 = lane & 15;
    const int id = blockIdx.x;
    const int qq = id >> 3, xcd = id & 7;
    const int m0 = (xcd * 128 + (qq >> 1)) * 128;
    const int n0 = (qq & 1) * 128;

    const f32x4 zf = {0.f, 0.f, 0.f, 0.f};
    f32x4 acc[4][4];
#pragma unroll
    for (int i = 0; i < 4; ++i)
#pragma unroll
        for (int j = 0; j < 4; ++j) acc[i][j] = zf;

    const int srow = wave * 16 + (lane >> 2);
    const int scol = (lane & 3) * 8;
    const short* Ap = A  + (long)(m0 + srow) * 256 + scol;
    const short* Bp = Bt + (long)(n0 + srow) * 256 + scol;
    short* lA = &As[wave * 512];
    short* lB = &Bs[wave * 512];

    for (int kt = 0; kt < 8; ++kt) {
        const int off = kt * 32;
        __syncthreads();
        gl_lds16(Ap + off,            lA);
        gl_lds16(Ap + 64 * 256 + off, lA + 2048);
        gl_lds16(Bp + off,            lB);
        gl_lds16(Bp + 64 * 256 + off, lB + 2048);
        __syncthreads();
        bf16x8 af[4], bfr[4];
#pragma unroll
        for (int i = 0; i < 4; ++i)
            af[i] = *(const bf16x8*)&As[(wm * 64 + i * 16 + l16) * 32 + quad * 8];
#pragma unroll
        for (int j = 0; j < 4; ++j)
            bfr[j] = *(const bf16x8*)&Bs[(wn * 64 + j * 16 + l16) * 32 + quad * 8];
#pragma unroll
        for (int i = 0; i < 4; ++i)
#pragma unroll
            for (int j = 0; j < 4; ++j)
                acc[i][j] = MFMA16(af[i], bfr[j], acc[i][j]);
    }

#pragma unroll
    for (int i = 0; i < 4; ++i)
#pragma unroll
        for (int r = 0; r < 4; ++r) {
            const long row = m0 + wm * 64 + i * 16 + quad * 4 + r;
#pragma unroll
            for (int j = 0; j < 4; ++j) {
                const int col = n0 + wn * 64 + j * 16 + l16;
                C[row * 256 + col] = acc[i][j][r] + bias[col];
            }
        }
}

// ---------------- window (local) attention: heads 0..3, seq=64, 1 wave/seq-head ----------------
__global__ __launch_bounds__(256)
void local_attn_kernel(const short* __restrict__ qkvL, short* __restrict__ attn) {
    __shared__ short sVT[4][32 * 72];   // V^T per wave
    __shared__ short sP[4][16 * 72];    // one 16-row P tile per wave
    const int tid  = threadIdx.x;
    const int lane = tid & 63, wave = tid >> 6;
    const int quad = lane >> 4, l16 = lane & 15;
    const int sh   = blockIdx.x * 4 + wave;       // < 8192
    const int head = sh & 3;
    const int win  = (sh >> 2) & 255;
    const int b    = sh >> 10;
    const int base_tok = b * 16384 + (win >> 4) * 1024 + (win & 15) * 8;
    const int ch = head * 32;
    const short* qb = qkvL + (long)sh * 6144;
    const short* kb = qb + 2048;
    const short* vp = qb + 4096;

    // stage V^T: lane = token, full 32-ch row (coalesced)
    {
        bf16x8 v0 = *(const bf16x8*)(vp + lane * 32);
        bf16x8 v1 = *(const bf16x8*)(vp + lane * 32 + 8);
        bf16x8 v2 = *(const bf16x8*)(vp + lane * 32 + 16);
        bf16x8 v3 = *(const bf16x8*)(vp + lane * 32 + 24);
#pragma unroll
        for (int d = 0; d < 8; ++d) {
            sVT[wave][(d     ) * 72 + lane] = v0[d];
            sVT[wave][(d +  8) * 72 + lane] = v1[d];
            sVT[wave][(d + 16) * 72 + lane] = v2[d];
            sVT[wave][(d + 24) * 72 + lane] = v3[d];
        }
    }
    __syncthreads();

    bf16x8 aq[4], bk[4];
#pragma unroll
    for (int i = 0; i < 4; ++i)
        aq[i] = *(const bf16x8*)(qb + (i * 16 + l16) * 32 + quad * 8);
#pragma unroll
    for (int j = 0; j < 4; ++j)
        bk[j] = *(const bf16x8*)(kb + (j * 16 + l16) * 32 + quad * 8);

    bf16x8 vbf[2][2];
#pragma unroll
    for (int kk = 0; kk < 2; ++kk)
#pragma unroll
        for (int j2 = 0; j2 < 2; ++j2)
            vbf[kk][j2] = *(const bf16x8*)&sVT[wave][(j2 * 16 + l16) * 72 + kk * 32 + quad * 8];

    const bf16x8 vone = {0x3F80, 0x3F80, 0x3F80, 0x3F80, 0x3F80, 0x3F80, 0x3F80, 0x3F80};
    const f32x4 zf = {0.f, 0.f, 0.f, 0.f};
    const bool evenL = (l16 & 1) == 0;

#pragma unroll
    for (int i = 0; i < 4; ++i) {
        f32x4 sa[4] = {zf, zf, zf, zf};
#pragma unroll
        for (int j = 0; j < 4; ++j)
            sa[j] = MFMA16(aq[i], bk[j], sa[j]);
#pragma unroll
        for (int j = 0; j < 4; ++j)
#pragma unroll
            for (int r = 0; r < 4; ++r)
                sP[wave][(quad * 4 + r) * 72 + j * 16 + l16] = pkb(__expf(sa[j][r]));
        __syncthreads();                       // sP visible (prophylactic)

        f32x4 o0 = zf, o1 = zf, os = zf;
#pragma unroll
        for (int kk = 0; kk < 2; ++kk) {
            const bf16x8 pa = *(const bf16x8*)&sP[wave][l16 * 72 + kk * 32 + quad * 8];
            o0 = MFMA16(pa, vbf[kk][0], o0);
            o1 = MFMA16(pa, vbf[kk][1], o1);
            os = MFMA16(pa, vone, os);
        }
        __syncthreads();                       // reads done before next overwrite

#pragma unroll
        for (int r = 0; r < 4; ++r) {
            const int s = i * 16 + quad * 4 + r;
            const int tok = base_tok + (s >> 3) * 128 + (s & 7);
            const float inv = 1.f / os[r];
            const float a0 = o0[r] * inv, a1 = o1[r] * inv;
            const float b0 = __shfl_xor(a0, 1), b1 = __shfl_xor(a1, 1);
            if (evenL) {
                *(unsigned*)&attn[(long)tok * 256 + ch + l16]      = pk2(a0, b0);
                *(unsigned*)&attn[(long)tok * 256 + ch + 16 + l16] = pk2(a1, b1);
            }
        }
    }
}

// ---------------- grid (global) attention: heads 4..7, seq=256, 1 block/seq-head ----------------
__global__ __launch_bounds__(256)
void global_attn_kernel(const short* __restrict__ qkvG, short* __restrict__ attn) {
    __shared__ short sVT[32 * 264];
    __shared__ short sP[4][16 * 72];
    const int tid  = threadIdx.x;
    const int lane = tid & 63, wave = tid >> 6;
    const int quad = lane >> 4, l16 = lane & 15;
    const int sh   = blockIdx.x;        // < 2048
    const int head = sh & 3;
    const int pos  = (sh >> 2) & 63;
    const int b    = sh >> 8;
    const int base_tok = b * 16384 + (pos >> 3) * 128 + (pos & 7);
    const int ch = (4 + head) * 32;
    const short* qb = qkvG + (long)sh * 24576;
    const short* kb = qb + 8192;
    const short* vp = qb + 16384;

    // stage V^T: thread = token (coalesced)
    {
        bf16x8 v0 = *(const bf16x8*)(vp + tid * 32);
        bf16x8 v1 = *(const bf16x8*)(vp + tid * 32 + 8);
        bf16x8 v2 = *(const bf16x8*)(vp + tid * 32 + 16);
        bf16x8 v3 = *(const bf16x8*)(vp + tid * 32 + 24);
#pragma unroll
        for (int d = 0; d < 8; ++d) {
            sVT[(d     ) * 264 + tid] = v0[d];
            sVT[(d +  8) * 264 + tid] = v1[d];
            sVT[(d + 16) * 264 + tid] = v2[d];
            sVT[(d + 24) * 264 + tid] = v3[d];
        }
    }
    __syncthreads();

    bf16x8 aq[4];
#pragma unroll
    for (int i = 0; i < 4; ++i)
        aq[i] = *(const bf16x8*)(qb + (wave * 64 + i * 16 + l16) * 32 + quad * 8);

    const bf16x8 vone = {0x3F80, 0x3F80, 0x3F80, 0x3F80, 0x3F80, 0x3F80, 0x3F80, 0x3F80};
    const f32x4 zf = {0.f, 0.f, 0.f, 0.f};
    f32x4 o0[4], o1[4], os[4];
#pragma unroll
    for (int i = 0; i < 4; ++i) { o0[i] = zf; o1[i] = zf; os[i] = zf; }

    for (int nc = 0; nc < 4; ++nc) {
        bf16x8 bk[4];
#pragma unroll
        for (int j = 0; j < 4; ++j)
            bk[j] = *(const bf16x8*)(kb + (nc * 64 + j * 16 + l16) * 32 + quad * 8);
        bf16x8 vbf[2][2];
#pragma unroll
        for (int kk = 0; kk < 2; ++kk)
#pragma unroll
            for (int j2 = 0; j2 < 2; ++j2)
                vbf[kk][j2] = *(const bf16x8*)&sVT[(j2 * 16 + l16) * 264 + nc * 64 + kk * 32 + quad * 8];

#pragma unroll
        for (int i = 0; i < 4; ++i) {
            f32x4 sa[4] = {zf, zf, zf, zf};
#pragma unroll
            for (int j = 0; j < 4; ++j)
                sa[j] = MFMA16(aq[i], bk[j], sa[j]);
#pragma unroll
            for (int j = 0; j < 4; ++j)
#pragma unroll
                for (int r = 0; r < 4; ++r)
                    sP[wave][(quad * 4 + r) * 72 + j * 16 + l16] = pkb(__expf(sa[j][r]));
            __syncthreads();                   // sP visible (prophylactic)
#pragma unroll
            for (int kk = 0; kk < 2; ++kk) {
                const bf16x8 pa = *(const bf16x8*)&sP[wave][l16 * 72 + kk * 32 + quad * 8];
                o0[i] = MFMA16(pa, vbf[kk][0], o0[i]);
                o1[i] = MFMA16(pa, vbf[kk][1], o1[i]);
                os[i] = MFMA16(pa, vone, os[i]);
            }
            __syncthreads();                   // reads done before next overwrite
        }
    }

    const bool evenL = (l16 & 1) == 0;
#pragma unroll
    for (int i = 0; i < 4; ++i)
#pragma unroll
        for (int r = 0; r < 4; ++r) {
            const int s = wave * 64 + i * 16 + quad * 4 + r;
            const int tok = base_tok + (s >> 4) * 1024 + (s & 15) * 8;
            const float inv = 1.f / os[i][r];
            const float a0 = o0[i][r] * inv, a1 = o1[i][r] * inv;
            const float b0 = __shfl_xor(a0, 1), b1 = __shfl_xor(a1, 1);
            if (evenL) {
                *(unsigned*)&attn[(long)tok * 256 + ch + l16]      = pk2(a0, b0);
                *(unsigned*)&attn[(long)tok * 256 + ch + 16 + l16] = pk2(a1, b1);
            }
        }
}

// ---------------- launch ----------------
extern "C" void kernel_launch(void* const* d_in, const int* in_sizes, int n_in,
                              void* d_out, int out_size, void* d_ws, size_t ws_size,
                              hipStream_t stream) {
    const float* x     = (const float*)d_in[0];
    const float* wqkv  = (const float*)d_in[1];
    const float* wproj = (const float*)d_in[2];
    const float* bproj = (const float*)d_in[3];

    char* ws = (char*)d_ws;
    short* xb   = (short*)(ws);                 //  67,108,864 B
    short* wqT  = (short*)(ws +  67108864);     //     393,216 B (q cols pre-scaled)
    short* wpT  = (short*)(ws +  67502080);     //     131,072 B
    short* qkvL = (short*)(ws +  67633152);     // 100,663,296 B  [8192][3][64][32]
    short* qkvG = (short*)(ws + 168296448);     // 100,663,296 B  [2048][3][256][32]
    short* attn = (short*)(ws + 268959744);     //  67,108,864 B  [131072][256]
    float* out  = (float*)d_out;

    cast_x_kernel<<<dim3(32768), dim3(256), 0, stream>>>(x, xb);
    cast_w_kernel<<<dim3(1024), dim3(256), 0, stream>>>(wqkv, wproj, wqT, wpT);
    gemm_qkv_kernel<<<dim3(6144), dim3(256), 0, stream>>>(xb, wqT, qkvL, qkvG);
    local_attn_kernel<<<dim3(2048), dim3(256), 0, stream>>>(qkvL, attn);
    global_attn_kernel<<<dim3(2048), dim3(256), 0, stream>>>(qkvG, attn);
    gemm_proj_kernel<<<dim3(2048), dim3(256), 0, stream>>>(attn, wpT, out, bproj);
}

// Round 5
// 449.198 us; speedup vs baseline: 1.0763x; 1.0763x over previous
//
#include <hip/hip_runtime.h>
#include <hip/hip_bf16.h>

using bf16x8 = __attribute__((ext_vector_type(8))) short;
using f32x4  = __attribute__((ext_vector_type(4))) float;

#define MFMA16(a, b, c) __builtin_amdgcn_mfma_f32_16x16x32_bf16((a), (b), (c), 0, 0, 0)

__device__ __forceinline__ short f2b(float f) {   // RNE bf16
    unsigned u = __builtin_bit_cast(unsigned, f);
    u = (u + 0x7fffu + ((u >> 16) & 1u)) >> 16;
    return (short)u;
}
__device__ __forceinline__ short pkb(float f) {   // round-to-nearest, ties away
    return (short)((__builtin_bit_cast(unsigned, f) + 0x8000u) >> 16);
}
__device__ __forceinline__ unsigned pk2(float lo, float hi) {  // two bf16 -> dword
    return (unsigned)(unsigned short)pkb(lo) | ((unsigned)(unsigned short)pkb(hi) << 16);
}
__device__ __forceinline__ void gl_lds16(const short* g, short* l) {
    __builtin_amdgcn_global_load_lds(
        (const __attribute__((address_space(1))) unsigned int*)g,
        (__attribute__((address_space(3))) unsigned int*)l, 16, 0, 0);
}

// ---------------- cast kernels ----------------
__global__ __launch_bounds__(256)
void cast_x_kernel(const float* __restrict__ x, short* __restrict__ xb) {
    const int i = blockIdx.x * 256 + threadIdx.x;   // float4 index, grid exact
    const float4 v = ((const float4*)x)[i];
    short4 o;
    o.x = f2b(v.x); o.y = f2b(v.y); o.z = f2b(v.z); o.w = f2b(v.w);
    ((short4*)xb)[i] = o;
}

__global__ __launch_bounds__(256)
void cast_w_kernel(const float* __restrict__ wqkv, const float* __restrict__ wproj,
                   short* __restrict__ wqT, short* __restrict__ wpT) {
    const int t = blockIdx.x * 256 + threadIdx.x;
    if (t < 768 * 256) {
        const int n = t >> 8, k = t & 255;
        float v = wqkv[k * 768 + n];
        if (n < 256) v *= 0.17677669529663687f;    // fold 1/sqrt(hd) into q columns
        wqT[t] = f2b(v);
    } else {
        const int u = t - 768 * 256;               // u < 65536
        const int n = u >> 8, k = u & 255;
        wpT[u] = f2b(wproj[k * 256 + n]);
    }
}

// ---------------- QKV GEMM with LDS-transpose coalesced epilogue ----------------
// m-block of 128 tokens == one image row (b, hrow), wcol 0..127.
// Local chunks: 16 windows x 4 heads x (8 ti x 32 ch = 512 B contiguous).
// Grid  chunks:  8 seqs    x 4 heads x (16 ti x 32 ch = 1 KB contiguous).
__global__ __launch_bounds__(256)
void gemm_qkv_kernel(const short* __restrict__ A, const short* __restrict__ Bt,
                     short* __restrict__ qkvL, short* __restrict__ qkvG) {
    __shared__ __align__(16) short smem[128 * 136];  // K-loop: As(4096)+Bs(4096); epilogue: Cs[128][136]
    short* As = smem;
    short* Bs = smem + 4096;
    const int tid  = threadIdx.x;
    const int lane = tid & 63, wave = tid >> 6;
    const int wm = wave >> 1, wn = wave & 1;
    const int quad = lane >> 4, l16 = lane & 15;
    const int id = blockIdx.x;
    const int qq = id >> 3, xcd = id & 7;
    const int m0 = (xcd * 128 + qq / 6) * 128;
    const int n0 = (qq % 6) * 128;

    const f32x4 zf = {0.f, 0.f, 0.f, 0.f};
    f32x4 acc[4][4];
#pragma unroll
    for (int i = 0; i < 4; ++i)
#pragma unroll
        for (int j = 0; j < 4; ++j) acc[i][j] = zf;

    const int srow = wave * 16 + (lane >> 2);
    const int scol = (lane & 3) * 8;
    const short* Ap = A  + (long)(m0 + srow) * 256 + scol;
    const short* Bp = Bt + (long)(n0 + srow) * 256 + scol;
    short* lA = &As[wave * 512];
    short* lB = &Bs[wave * 512];

    for (int kt = 0; kt < 8; ++kt) {
        const int off = kt * 32;
        __syncthreads();
        gl_lds16(Ap + off,            lA);
        gl_lds16(Ap + 64 * 256 + off, lA + 2048);
        gl_lds16(Bp + off,            lB);
        gl_lds16(Bp + 64 * 256 + off, lB + 2048);
        __syncthreads();
        bf16x8 af[4], bfr[4];
#pragma unroll
        for (int i = 0; i < 4; ++i)
            af[i] = *(const bf16x8*)&As[(wm * 64 + i * 16 + l16) * 32 + quad * 8];
#pragma unroll
        for (int j = 0; j < 4; ++j)
            bfr[j] = *(const bf16x8*)&Bs[(wn * 64 + j * 16 + l16) * 32 + quad * 8];
#pragma unroll
        for (int i = 0; i < 4; ++i)
#pragma unroll
            for (int j = 0; j < 4; ++j)
                acc[i][j] = MFMA16(af[i], bfr[j], acc[i][j]);
    }

    // ---- epilogue phase 1: acc -> Cs[128 rows=wcol][136] as bf16 ----
    __syncthreads();                            // As/Bs fully consumed; reuse as Cs
    short* Cs = smem;
    {
        const int crow = wm * 64 + quad * 4;
        const int ccol = wn * 64 + l16;
#pragma unroll
        for (int i = 0; i < 4; ++i)
#pragma unroll
            for (int j = 0; j < 4; ++j)
#pragma unroll
                for (int r = 0; r < 4; ++r)
                    Cs[(crow + i * 16 + r) * 136 + ccol + j * 16] = pkb(acc[i][j][r]);
    }
    __syncthreads();

    // ---- epilogue phase 2: coalesced chunk stores ----
    const int part = n0 >> 8;                   // 0=q 1=k 2=v (block-uniform)
    const bool isLocal = ((n0 >> 7) & 1) == 0;  // heads 0..3 vs 4..7
    const int b    = m0 >> 14;
    const int hrow = (m0 >> 7) & 127;
    if (isLocal) {
        short* dst0 = qkvL + part * 2048;
        const int win_hi = (hrow >> 3) << 4;
        const int ti0    = (hrow & 7) * 8;
        const int t  = lane >> 3;               // 0..7   (ti within chunk)
        const int s4 = (lane & 7) * 4;          // shorts within 32-ch row
#pragma unroll
        for (int c = 0; c < 16; ++c) {
            const int idx = wave * 16 + c;
            const int wi = idx >> 2, h = idx & 3;
            const ushort4 v = *(const ushort4*)&Cs[(wi * 8 + t) * 136 + h * 32 + s4];
            short* dp = dst0 + (long)(((b << 8) | (win_hi | wi)) * 4 + h) * 6144 + ti0 * 32;
            *(ushort4*)&dp[lane * 4] = v;       // 512 B contiguous per chunk
        }
    } else {
        short* dst0 = qkvG + part * 8192;
        const int pos0 = (hrow & 7) * 8;
        const int tib  = (hrow >> 3) * 16;
        const int tt = lane >> 2;               // 0..15  (ti within chunk)
        const int s8 = (lane & 3) * 8;
#pragma unroll
        for (int c = 0; c < 8; ++c) {
            const int idx = wave * 8 + c;
            const int p = idx >> 2, h = idx & 3;
            const bf16x8 v = *(const bf16x8*)&Cs[(p + tt * 8) * 136 + h * 32 + s8];
            short* dp = dst0 + (long)(((b << 6) | (pos0 + p)) * 4 + h) * 24576 + tib * 32;
            *(bf16x8*)&dp[lane * 8] = v;        // 1 KB contiguous per chunk
        }
    }
}

// ---------------- proj GEMM: [131072 x 256] x [256 x 256]^T + bias, fp32 out ----------------
__global__ __launch_bounds__(256)
void gemm_proj_kernel(const short* __restrict__ A, const short* __restrict__ Bt,
                      float* __restrict__ C, const float* __restrict__ bias) {
    __shared__ short As[128 * 32];
    __shared__ short Bs[128 * 32];
    const int tid  = threadIdx.x;
    const int lane = tid & 63, wave = tid >> 6;
    const int wm = wave >> 1, wn = wave & 1;
    const int quad = lane >> 4, l16 = lane & 15;
    const int id = blockIdx.x;
    const int qq = id >> 3, xcd = id & 7;
    const int m0 = (xcd * 128 + (qq >> 1)) * 128;
    const int n0 = (qq & 1) * 128;

    const f32x4 zf = {0.f, 0.f, 0.f, 0.f};
    f32x4 acc[4][4];
#pragma unroll
    for (int i = 0; i < 4; ++i)
#pragma unroll
        for (int j = 0; j < 4; ++j) acc[i][j] = zf;

    const int srow = wave * 16 + (lane >> 2);
    const int scol = (lane & 3) * 8;
    const short* Ap = A  + (long)(m0 + srow) * 256 + scol;
    const short* Bp = Bt + (long)(n0 + srow) * 256 + scol;
    short* lA = &As[wave * 512];
    short* lB = &Bs[wave * 512];

    for (int kt = 0; kt < 8; ++kt) {
        const int off = kt * 32;
        __syncthreads();
        gl_lds16(Ap + off,            lA);
        gl_lds16(Ap + 64 * 256 + off, lA + 2048);
        gl_lds16(Bp + off,            lB);
        gl_lds16(Bp + 64 * 256 + off, lB + 2048);
        __syncthreads();
        bf16x8 af[4], bfr[4];
#pragma unroll
        for (int i = 0; i < 4; ++i)
            af[i] = *(const bf16x8*)&As[(wm * 64 + i * 16 + l16) * 32 + quad * 8];
#pragma unroll
        for (int j = 0; j < 4; ++j)
            bfr[j] = *(const bf16x8*)&Bs[(wn * 64 + j * 16 + l16) * 32 + quad * 8];
#pragma unroll
        for (int i = 0; i < 4; ++i)
#pragma unroll
            for (int j = 0; j < 4; ++j)
                acc[i][j] = MFMA16(af[i], bfr[j], acc[i][j]);
    }

#pragma unroll
    for (int i = 0; i < 4; ++i)
#pragma unroll
        for (int r = 0; r < 4; ++r) {
            const long row = m0 + wm * 64 + i * 16 + quad * 4 + r;
#pragma unroll
            for (int j = 0; j < 4; ++j) {
                const int col = n0 + wn * 64 + j * 16 + l16;
                C[row * 256 + col] = acc[i][j][r] + bias[col];
            }
        }
}

// ---------------- window (local) attention: heads 0..3, seq=64, 1 wave/seq-head ----------------
__global__ __launch_bounds__(256)
void local_attn_kernel(const short* __restrict__ qkvL, short* __restrict__ attn) {
    __shared__ short sVT[4][32 * 72];   // V^T per wave
    __shared__ short sP[4][16 * 72];    // one 16-row P tile per wave
    const int tid  = threadIdx.x;
    const int lane = tid & 63, wave = tid >> 6;
    const int quad = lane >> 4, l16 = lane & 15;
    const int sh   = blockIdx.x * 4 + wave;       // < 8192
    const int head = sh & 3;
    const int win  = (sh >> 2) & 255;
    const int b    = sh >> 10;
    const int base_tok = b * 16384 + (win >> 4) * 1024 + (win & 15) * 8;
    const int ch = head * 32;
    const short* qb = qkvL + (long)sh * 6144;
    const short* kb = qb + 2048;
    const short* vp = qb + 4096;

    // stage V^T: lane = token, full 32-ch row (coalesced)
    {
        bf16x8 v0 = *(const bf16x8*)(vp + lane * 32);
        bf16x8 v1 = *(const bf16x8*)(vp + lane * 32 + 8);
        bf16x8 v2 = *(const bf16x8*)(vp + lane * 32 + 16);
        bf16x8 v3 = *(const bf16x8*)(vp + lane * 32 + 24);
#pragma unroll
        for (int d = 0; d < 8; ++d) {
            sVT[wave][(d     ) * 72 + lane] = v0[d];
            sVT[wave][(d +  8) * 72 + lane] = v1[d];
            sVT[wave][(d + 16) * 72 + lane] = v2[d];
            sVT[wave][(d + 24) * 72 + lane] = v3[d];
        }
    }
    __syncthreads();

    bf16x8 aq[4], bk[4];
#pragma unroll
    for (int i = 0; i < 4; ++i)
        aq[i] = *(const bf16x8*)(qb + (i * 16 + l16) * 32 + quad * 8);
#pragma unroll
    for (int j = 0; j < 4; ++j)
        bk[j] = *(const bf16x8*)(kb + (j * 16 + l16) * 32 + quad * 8);

    bf16x8 vbf[2][2];
#pragma unroll
    for (int kk = 0; kk < 2; ++kk)
#pragma unroll
        for (int j2 = 0; j2 < 2; ++j2)
            vbf[kk][j2] = *(const bf16x8*)&sVT[wave][(j2 * 16 + l16) * 72 + kk * 32 + quad * 8];

    const bf16x8 vone = {0x3F80, 0x3F80, 0x3F80, 0x3F80, 0x3F80, 0x3F80, 0x3F80, 0x3F80};
    const f32x4 zf = {0.f, 0.f, 0.f, 0.f};
    const bool evenL = (l16 & 1) == 0;

#pragma unroll
    for (int i = 0; i < 4; ++i) {
        f32x4 sa[4] = {zf, zf, zf, zf};
#pragma unroll
        for (int j = 0; j < 4; ++j)
            sa[j] = MFMA16(aq[i], bk[j], sa[j]);
#pragma unroll
        for (int j = 0; j < 4; ++j)
#pragma unroll
            for (int r = 0; r < 4; ++r)
                sP[wave][(quad * 4 + r) * 72 + j * 16 + l16] = pkb(__expf(sa[j][r]));
        // sP is wave-private: lgkmcnt ordering suffices (R2-proven)

        f32x4 o0 = zf, o1 = zf, os = zf;
#pragma unroll
        for (int kk = 0; kk < 2; ++kk) {
            const bf16x8 pa = *(const bf16x8*)&sP[wave][l16 * 72 + kk * 32 + quad * 8];
            o0 = MFMA16(pa, vbf[kk][0], o0);
            o1 = MFMA16(pa, vbf[kk][1], o1);
            os = MFMA16(pa, vone, os);
        }

#pragma unroll
        for (int r = 0; r < 4; ++r) {
            const int s = i * 16 + quad * 4 + r;
            const int tok = base_tok + (s >> 3) * 128 + (s & 7);
            const float inv = 1.f / os[r];
            const float a0 = o0[r] * inv, a1 = o1[r] * inv;
            const float b0 = __shfl_xor(a0, 1), b1 = __shfl_xor(a1, 1);
            if (evenL) {
                *(unsigned*)&attn[(long)tok * 256 + ch + l16]      = pk2(a0, b0);
                *(unsigned*)&attn[(long)tok * 256 + ch + 16 + l16] = pk2(a1, b1);
            }
        }
    }
}

// ---------------- grid (global) attention: heads 4..7, seq=256, 1 block/seq-head ----------------
__global__ __launch_bounds__(256)
void global_attn_kernel(const short* __restrict__ qkvG, short* __restrict__ attn) {
    __shared__ short sVT[32 * 264];
    __shared__ short sP[4][16 * 72];
    const int tid  = threadIdx.x;
    const int lane = tid & 63, wave = tid >> 6;
    const int quad = lane >> 4, l16 = lane & 15;
    const int sh   = blockIdx.x;        // < 2048
    const int head = sh & 3;
    const int pos  = (sh >> 2) & 63;
    const int b    = sh >> 8;
    const int base_tok = b * 16384 + (pos >> 3) * 128 + (pos & 7);
    const int ch = (4 + head) * 32;
    const short* qb = qkvG + (long)sh * 24576;
    const short* kb = qb + 8192;
    const short* vp = qb + 16384;

    // stage V^T: thread = token (coalesced)
    {
        bf16x8 v0 = *(const bf16x8*)(vp + tid * 32);
        bf16x8 v1 = *(const bf16x8*)(vp + tid * 32 + 8);
        bf16x8 v2 = *(const bf16x8*)(vp + tid * 32 + 16);
        bf16x8 v3 = *(const bf16x8*)(vp + tid * 32 + 24);
#pragma unroll
        for (int d = 0; d < 8; ++d) {
            sVT[(d     ) * 264 + tid] = v0[d];
            sVT[(d +  8) * 264 + tid] = v1[d];
            sVT[(d + 16) * 264 + tid] = v2[d];
            sVT[(d + 24) * 264 + tid] = v3[d];
        }
    }
    __syncthreads();                    // sVT block-shared: barrier required

    bf16x8 aq[4];
#pragma unroll
    for (int i = 0; i < 4; ++i)
        aq[i] = *(const bf16x8*)(qb + (wave * 64 + i * 16 + l16) * 32 + quad * 8);

    const bf16x8 vone = {0x3F80, 0x3F80, 0x3F80, 0x3F80, 0x3F80, 0x3F80, 0x3F80, 0x3F80};
    const f32x4 zf = {0.f, 0.f, 0.f, 0.f};
    f32x4 o0[4], o1[4], os[4];
#pragma unroll
    for (int i = 0; i < 4; ++i) { o0[i] = zf; o1[i] = zf; os[i] = zf; }

    for (int nc = 0; nc < 4; ++nc) {
        bf16x8 bk[4];
#pragma unroll
        for (int j = 0; j < 4; ++j)
            bk[j] = *(const bf16x8*)(kb + (nc * 64 + j * 16 + l16) * 32 + quad * 8);
        bf16x8 vbf[2][2];
#pragma unroll
        for (int kk = 0; kk < 2; ++kk)
#pragma unroll
            for (int j2 = 0; j2 < 2; ++j2)
                vbf[kk][j2] = *(const bf16x8*)&sVT[(j2 * 16 + l16) * 264 + nc * 64 + kk * 32 + quad * 8];

#pragma unroll
        for (int i = 0; i < 4; ++i) {
            f32x4 sa[4] = {zf, zf, zf, zf};
#pragma unroll
            for (int j = 0; j < 4; ++j)
                sa[j] = MFMA16(aq[i], bk[j], sa[j]);
#pragma unroll
            for (int j = 0; j < 4; ++j)
#pragma unroll
                for (int r = 0; r < 4; ++r)
                    sP[wave][(quad * 4 + r) * 72 + j * 16 + l16] = pkb(__expf(sa[j][r]));
            // sP is wave-private: no barrier (R2-proven)
#pragma unroll
            for (int kk = 0; kk < 2; ++kk) {
                const bf16x8 pa = *(const bf16x8*)&sP[wave][l16 * 72 + kk * 32 + quad * 8];
                o0[i] = MFMA16(pa, vbf[kk][0], o0[i]);
                o1[i] = MFMA16(pa, vbf[kk][1], o1[i]);
                os[i] = MFMA16(pa, vone, os[i]);
            }
        }
    }

    const bool evenL = (l16 & 1) == 0;
#pragma unroll
    for (int i = 0; i < 4; ++i)
#pragma unroll
        for (int r = 0; r < 4; ++r) {
            const int s = wave * 64 + i * 16 + quad * 4 + r;
            const int tok = base_tok + (s >> 4) * 1024 + (s & 15) * 8;
            const float inv = 1.f / os[i][r];
            const float a0 = o0[i][r] * inv, a1 = o1[i][r] * inv;
            const float b0 = __shfl_xor(a0, 1), b1 = __shfl_xor(a1, 1);
            if (evenL) {
                *(unsigned*)&attn[(long)tok * 256 + ch + l16]      = pk2(a0, b0);
                *(unsigned*)&attn[(long)tok * 256 + ch + 16 + l16] = pk2(a1, b1);
            }
        }
}

// ---------------- launch ----------------
extern "C" void kernel_launch(void* const* d_in, const int* in_sizes, int n_in,
                              void* d_out, int out_size, void* d_ws, size_t ws_size,
                              hipStream_t stream) {
    const float* x     = (const float*)d_in[0];
    const float* wqkv  = (const float*)d_in[1];
    const float* wproj = (const float*)d_in[2];
    const float* bproj = (const float*)d_in[3];

    char* ws = (char*)d_ws;
    short* xb   = (short*)(ws);                 //  67,108,864 B
    short* wqT  = (short*)(ws +  67108864);     //     393,216 B (q cols pre-scaled)
    short* wpT  = (short*)(ws +  67502080);     //     131,072 B
    short* qkvL = (short*)(ws +  67633152);     // 100,663,296 B  [8192][3][64][32]
    short* qkvG = (short*)(ws + 168296448);     // 100,663,296 B  [2048][3][256][32]
    short* attn = (short*)(ws + 268959744);     //  67,108,864 B  [131072][256]
    float* out  = (float*)d_out;

    cast_x_kernel<<<dim3(32768), dim3(256), 0, stream>>>(x, xb);
    cast_w_kernel<<<dim3(1024), dim3(256), 0, stream>>>(wqkv, wproj, wqT, wpT);
    gemm_qkv_kernel<<<dim3(6144), dim3(256), 0, stream>>>(xb, wqT, qkvL, qkvG);
    local_attn_kernel<<<dim3(2048), dim3(256), 0, stream>>>(qkvL, attn);
    global_attn_kernel<<<dim3(2048), dim3(256), 0, stream>>>(qkvG, attn);
    gemm_proj_kernel<<<dim3(2048), dim3(256), 0, stream>>>(attn, wpT, out, bproj);
}